// Round 10
// baseline (138.889 us; speedup 1.0000x reference)
//
#include <hip/hip_runtime.h>
#include <cmath>

// MoE router via 3-way bf16-split MFMA emulation of fp32 GEMM, compensated
// (TwoSum) accumulation. R10: occupancy push to 20 waves/CU.
//  - VGPR bucket for 5 waves/SIMD is <=102 (pool 512/SIMD): register diet via
//    2 X-buffers (WAR reuse), per-n B transients, single-f32 partials.
//  - LDS double-buffer 24 KB + __launch_bounds__(256,5) -> 5 blocks/CU.
//  - NPART=8 (grid 2048) so 5 blocks/CU are actually resident.
//  - Partials: one f32 (sum+comp rounded, err ~3e-8/part); topk TwoSum-chains
//    the 8 parts exactly -> logit err ~8.5e-8, 20x under the R2 flip point.
//  - Queue invariant: iter c entry [X(c+1)]; CONVERT(Xc); STAGE(c+1);
//    LOADX(c+2); MFMA; vmcnt(2) retires X(c+1)+S(c+1); barrier.
//
// logits[T,64] = x[T,4096] @ w[64,4096]^T, sigmoid, top-8 on prob+bias,
// weights = p/sum*2.5. Outputs: weights[T,8] f32, then indices[T,8] as f32.

typedef float f32x4 __attribute__((ext_vector_type(4)));
typedef short s16x8 __attribute__((ext_vector_type(8)));
typedef unsigned int u32;
typedef u32 u32x4 __attribute__((ext_vector_type(4)));

#define E_DIM 64
#define KC 32
#define CH_BYTES 12288   // 3 splits * 4 ntiles * 64 lanes * 16B
#define NPART 8
#define HI_OFF (2u << 20)   // partials start at 2 MB (w3 is 1.5 MB)

union V16 { u32x4 u; s16x8 s; };

__device__ __forceinline__ unsigned short f2bf(float f) {
  unsigned u = __float_as_uint(f);
  u += 0x7fffu + ((u >> 16) & 1u);   // round-to-nearest-even
  return (unsigned short)(u >> 16);
}
__device__ __forceinline__ float bf2f(unsigned short s) {
  return __uint_as_float(((unsigned)s) << 16);
}

// ---- kernel W: split w into 3 bf16 planes, in per-lane B-fragment layout ----
// w3[c][s][n][lane]*16B ; lane holds expert e=n*16+(lane&15),
// k = c*32 + (lane>>4)*8 + j  (j=0..7 within the 16B slot).
__global__ __launch_bounds__(256) void split_w(
    const float* __restrict__ w, unsigned char* __restrict__ w3, int Hdim)
{
  const int kpr = Hdim >> 4;                      // 16-elem k-groups per row
  const int g = blockIdx.x * 256 + threadIdx.x;
  const int e = g / kpr;
  const int k0 = (g - e * kpr) * 16;
  if (e >= E_DIM) return;

  const float* src = w + (size_t)e * Hdim + k0;
  float f[16];
#pragma unroll
  for (int i = 0; i < 4; ++i) {
    float4 v = *(const float4*)(src + i * 4);
    f[i*4+0] = v.x; f[i*4+1] = v.y; f[i*4+2] = v.z; f[i*4+3] = v.w;
  }
  unsigned short hs[16], ms[16], ls[16];
#pragma unroll
  for (int i = 0; i < 16; ++i) {
    unsigned short h = f2bf(f[i]);
    float r1 = f[i] - bf2f(h);
    unsigned short m = f2bf(r1);
    float r2 = r1 - bf2f(m);
    hs[i] = h; ms[i] = m; ls[i] = f2bf(r2);
  }
  const int c  = k0 >> 5;                          // chunk of 32 k
  const int n  = e >> 4;                           // n-tile
  const int la = (e & 15) + (((k0 & 31) >> 3) << 4);  // lane of first 8 elems
  unsigned char* base = w3 + (size_t)c * CH_BYTES + n * 1024;

#define STORE_SPLIT(arr, s)                                              \
  do {                                                                   \
    s16x8 pa, pb;                                                        \
    _Pragma("unroll")                                                    \
    for (int j = 0; j < 8; ++j) { pa[j] = (short)arr[j]; pb[j] = (short)arr[8+j]; } \
    *(s16x8*)(base + (s)*4096 + la * 16)        = pa;                    \
    *(s16x8*)(base + (s)*4096 + (la + 16) * 16) = pb;                    \
  } while (0)

  STORE_SPLIT(hs, 0);
  STORE_SPLIT(ms, 1);
  STORE_SPLIT(ls, 2);
#undef STORE_SPLIT
}

// ---- kernel G: dbuf LDS, counted-vmcnt, 20 waves/CU MFMA GEMM ----
__global__ __launch_bounds__(256, 5) void router_mfma(
    const float* __restrict__ x, const unsigned char* __restrict__ w3,
    const float* __restrict__ bias, float* __restrict__ outw,
    float* __restrict__ outi, float* __restrict__ pp,
    int T, int Hdim)
{
  __shared__ __align__(16) unsigned char lds[2][CH_BYTES];  // 24 KB

  const int tid  = threadIdx.x;
  const int wid  = tid >> 6;
  const int lane = tid & 63;
  const int lc   = lane & 15;   // token row / expert col / D col
  const int lq   = lane >> 4;   // k-slot group / D row group
  const int by   = blockIdx.y;
  const int nch  = Hdim / KC / gridDim.y;   // 16 (128 in fallback)
  const int t0   = blockIdx.x * 64;

  const float* xp = x + (size_t)(t0 + wid * 16 + lc) * Hdim
                      + (size_t)by * nch * KC + lq * 8;
  const unsigned char* w3p = w3 + (size_t)by * nch * CH_BYTES;

  f32x4 acc[4], sum_[4], comp[4];
#pragma unroll
  for (int n = 0; n < 4; ++n) {
    acc[n] = (f32x4){0,0,0,0};
    sum_[n] = (f32x4){0,0,0,0};
    comp[n] = (f32x4){0,0,0,0};
  }

#define SB()     __builtin_amdgcn_sched_barrier(0)
#define WAITV2() asm volatile("s_waitcnt vmcnt(2)" ::: "memory")
#define WAITV0() asm volatile("s_waitcnt vmcnt(0)" ::: "memory")
#define BAR()    __builtin_amdgcn_s_barrier()

  // stage chunk c into lds[b]: 3 x 16B per thread, linear (gload_lds-safe)
#define STAGE(c, b)                                                          \
  do {                                                                       \
    const unsigned char* gs = w3p + (size_t)(c) * CH_BYTES + tid * 16;       \
    unsigned char* ld_ = &lds[b][0] + tid * 16;                              \
    _Pragma("unroll")                                                        \
    for (int i = 0; i < 3; ++i)                                              \
      __builtin_amdgcn_global_load_lds(                                      \
          (const __attribute__((address_space(1))) unsigned int*)(gs + i*4096), \
          (__attribute__((address_space(3))) unsigned int*)(ld_ + i*4096),   \
          16, 0, 0);                                                         \
  } while (0)

#define LOADX(c, X)                                                          \
  do {                                                                       \
    X[0] = *(const float4*)(xp + (size_t)(c) * KC);                          \
    X[1] = *(const float4*)(xp + (size_t)(c) * KC + 4);                      \
  } while (0)

  // round-half-up bf16 split + v_perm pack: f = h + m + l, err ~2^-24|f|.
#define SPLIT_PAIR(f0, f1, i, AHU, AMU, ALU)                                 \
  do {                                                                       \
    u32 u0_ = __float_as_uint(f0), u1_ = __float_as_uint(f1);                \
    u32 v0_ = u0_ + 0x8000u, v1_ = u1_ + 0x8000u;                            \
    AHU[i] = __builtin_amdgcn_perm(v1_, v0_, 0x07060302u);                   \
    float r0_ = (f0) - __uint_as_float(v0_ & 0xffff0000u);                   \
    float r1_ = (f1) - __uint_as_float(v1_ & 0xffff0000u);                   \
    u32 w0_ = __float_as_uint(r0_) + 0x8000u;                                \
    u32 w1_ = __float_as_uint(r1_) + 0x8000u;                                \
    AMU[i] = __builtin_amdgcn_perm(w1_, w0_, 0x07060302u);                   \
    float s0_ = r0_ - __uint_as_float(w0_ & 0xffff0000u);                    \
    float s1_ = r1_ - __uint_as_float(w1_ & 0xffff0000u);                    \
    u32 y0_ = __float_as_uint(s0_) + 0x8000u;                                \
    u32 y1_ = __float_as_uint(s1_) + 0x8000u;                                \
    ALU[i] = __builtin_amdgcn_perm(y1_, y0_, 0x07060302u);                   \
  } while (0)

#define CONVERT(X)                                                           \
  do {                                                                       \
    V16 ah_, am_, al_;                                                       \
    SPLIT_PAIR(X[0].x, X[0].y, 0, ah_.u, am_.u, al_.u);                      \
    SPLIT_PAIR(X[0].z, X[0].w, 1, ah_.u, am_.u, al_.u);                      \
    SPLIT_PAIR(X[1].x, X[1].y, 2, ah_.u, am_.u, al_.u);                      \
    SPLIT_PAIR(X[1].z, X[1].w, 3, ah_.u, am_.u, al_.u);                      \
    Aah = ah_.s; Aam = am_.s; Aal = al_.s;                                   \
  } while (0)

  // 24 MFMAs; per-n B transients (12 VGPR live) to fit the 102-reg bucket.
#define MFMA_ALL(b)                                                          \
  do {                                                                       \
    const unsigned char* B_ = &lds[b][0] + lane * 16;                        \
    __builtin_amdgcn_s_setprio(1);                                           \
    _Pragma("unroll")                                                        \
    for (int n = 0; n < 4; ++n) {                                            \
      s16x8 bh = *(const s16x8*)(B_ + 0*4096 + n*1024);                      \
      s16x8 bm = *(const s16x8*)(B_ + 1*4096 + n*1024);                      \
      s16x8 bl = *(const s16x8*)(B_ + 2*4096 + n*1024);                      \
      acc[n] = __builtin_amdgcn_mfma_f32_16x16x32_bf16(Aah, bh, acc[n], 0,0,0); \
      acc[n] = __builtin_amdgcn_mfma_f32_16x16x32_bf16(Aah, bm, acc[n], 0,0,0); \
      acc[n] = __builtin_amdgcn_mfma_f32_16x16x32_bf16(Aam, bh, acc[n], 0,0,0); \
      acc[n] = __builtin_amdgcn_mfma_f32_16x16x32_bf16(Aah, bl, acc[n], 0,0,0); \
      acc[n] = __builtin_amdgcn_mfma_f32_16x16x32_bf16(Aam, bm, acc[n], 0,0,0); \
      acc[n] = __builtin_amdgcn_mfma_f32_16x16x32_bf16(Aal, bh, acc[n], 0,0,0); \
    }                                                                        \
    __builtin_amdgcn_s_setprio(0);                                           \
  } while (0)

  // TwoSum fold: (sum_,comp) += acc exactly; acc reset. Adds/subs only.
#define FOLD()                                                               \
  do {                                                                       \
    _Pragma("unroll")                                                        \
    for (int n = 0; n < 4; ++n)                                              \
      _Pragma("unroll")                                                      \
      for (int r = 0; r < 4; ++r) {                                          \
        float a_ = acc[n][r];                                                \
        float s_ = sum_[n][r];                                               \
        float t_ = s_ + a_;                                                  \
        float z_ = t_ - s_;                                                  \
        comp[n][r] += (s_ - (t_ - z_)) + (a_ - z_);                          \
        sum_[n][r] = t_;                                                     \
        acc[n][r] = 0.f;                                                     \
      }                                                                      \
  } while (0)

  // Iter c (entry queue [X(c+1)]): consume X(c) from XBUF, stage c+1,
  // reload XBUF with X(c+2) (WAR reuse). vmcnt(2) retires X(c+1)+S(c+1),
  // leaves X(c+2) in flight across the barrier.
#define ITER(c, XBUF)                                                        \
  do {                                                                       \
    CONVERT(XBUF);                                                           \
    STAGE((c) + 1, ((c) + 1) & 1);                                           \
    LOADX((c) + 2, XBUF);                                                    \
    SB();                                                                    \
    MFMA_ALL((c) & 1);                                                       \
    WAITV2();                                                                \
    BAR();                                                                   \
    SB();                                                                    \
  } while (0)

  float4 XA[2], XB[2];
  s16x8 Aah, Aam, Aal;

  // prologue: S0, X0, X1; retire S0 for all waves, then barrier (no race).
  STAGE(0, 0);
  LOADX(0, XA);
  LOADX(1, XB);
  asm volatile("s_waitcnt vmcnt(4)" ::: "memory");
  BAR();
  SB();

#pragma unroll 1
  for (int c = 0; c < nch - 4; c += 4) {
    ITER(c + 0, XA);
    ITER(c + 1, XB);
    ITER(c + 2, XA);
    ITER(c + 3, XB);
    FOLD();
  }
  // final 4 chunks: 2 full iters, then 2 compute-only tails
  ITER(nch - 4, XA);
  ITER(nch - 3, XB);
  {  // chunk nch-2 (buf 0): stage last chunk, full drain
    CONVERT(XA);
    STAGE(nch - 1, 1);
    SB();
    MFMA_ALL(0);
    WAITV0();
    BAR();
    SB();
    // chunk nch-1 (buf 1): compute only
    CONVERT(XB);
    SB();
    MFMA_ALL(1);
    FOLD();
  }

  if (gridDim.y != 1) {
    // ---- partial mode: single f32 (sum+comp rounded once, err ~3e-8) ----
#pragma unroll
    for (int n = 0; n < 4; ++n)
#pragma unroll
      for (int r = 0; r < 4; ++r) {
        const int tok = t0 + wid * 16 + lq * 4 + r;
        const size_t o = ((size_t)tok * NPART + by) * E_DIM + n * 16 + lc;
        pp[o] = sum_[n][r] + comp[n][r];
      }
    return;
  }

  // ---- fused epilogue (fallback, gridDim.y==1) ----
  float bias_v[4];
#pragma unroll
  for (int n = 0; n < 4; ++n) bias_v[n] = bias[n * 16 + lc];

  float pr[4][4], bi[4][4];
#pragma unroll
  for (int n = 0; n < 4; ++n)
#pragma unroll
    for (int r = 0; r < 4; ++r) {
      float logit = sum_[n][r] + comp[n][r];
      float p = 1.0f / (1.0f + expf(-logit));
      pr[n][r] = p;
      bi[n][r] = p + bias_v[n];
    }
#pragma unroll
  for (int r = 0; r < 4; ++r) {
    float v0 = bi[0][r], v1 = bi[1][r], v2 = bi[2][r], v3 = bi[3][r];
    float p0 = pr[0][r], p1 = pr[1][r], p2 = pr[2][r], p3 = pr[3][r];
    float sum = 0.f, selp = 0.f;
    int seli = 0;
#pragma unroll
    for (int k = 0; k < 8; ++k) {
      float bv = v0; int bn = 0; float bp = p0;
      if (v1 > bv) { bv = v1; bn = 1; bp = p1; }
      if (v2 > bv) { bv = v2; bn = 2; bp = p2; }
      if (v3 > bv) { bv = v3; bn = 3; bp = p3; }
      int be = bn * 16 + lc;
#pragma unroll
      for (int off = 8; off >= 1; off >>= 1) {
        float ov = __shfl_xor(bv, off);
        float op = __shfl_xor(bp, off);
        int   oe = __shfl_xor(be, off);
        if (ov > bv || (ov == bv && oe < be)) { bv = ov; bp = op; be = oe; }
      }
      sum += bp;
      if (lc == k) { selp = bp; seli = be; }
      if (lc == (be & 15)) {
        int gsel = be >> 4;
        if      (gsel == 0) v0 = -1e30f;
        else if (gsel == 1) v1 = -1e30f;
        else if (gsel == 2) v2 = -1e30f;
        else                v3 = -1e30f;
      }
    }
    if (lc < 8) {
      const int tok = t0 + wid * 16 + lq * 4 + r;
      outw[(size_t)tok * 8 + lc] = selp * 2.5f / (sum + 1e-20f);
      outi[(size_t)tok * 8 + lc] = (float)seli;
    }
  }
}

// ---- kernel T: TwoSum-combine 8 partials + sigmoid + top-8 ----
__global__ __launch_bounds__(256) void router_topk(
    const float* __restrict__ pp, const float* __restrict__ bias,
    float* __restrict__ outw, float* __restrict__ outi, int T)
{
  const int lane = threadIdx.x & 63;
  const int t = blockIdx.x * 4 + (threadIdx.x >> 6);
  if (t >= T) return;

  float s = 0.f, c = 0.f;
#pragma unroll
  for (int p = 0; p < NPART; ++p) {
    float a = pp[((size_t)t * NPART + p) * E_DIM + lane];
    float tt = s + a;
    float z = tt - s;
    c += (s - (tt - z)) + (a - z);
    s = tt;
  }
  const float logit = s + c;

  const float prob = 1.0f / (1.0f + expf(-logit));
  float v = prob + bias[lane];

  float sum = 0.f, selw = 0.f;
  int seli = 0;
#pragma unroll
  for (int k = 0; k < 8; ++k) {
    float rv = v;
    int   ri = lane;
#pragma unroll
    for (int off = 32; off > 0; off >>= 1) {
      float ov = __shfl_xor(rv, off);
      int   oi = __shfl_xor(ri, off);
      if (ov > rv || (ov == rv && oi < ri)) { rv = ov; ri = oi; }
    }
    float pwin = __shfl(prob, ri);
    sum += pwin;
    if (lane == k)  { selw = pwin; seli = ri; }
    if (lane == ri) v = -INFINITY;
  }

  if (lane < 8) {
    float scale = 2.5f / (sum + 1e-20f);
    outw[(size_t)t * 8 + lane] = selw * scale;
    outi[(size_t)t * 8 + lane] = (float)seli;
  }
}

extern "C" void kernel_launch(void* const* d_in, const int* in_sizes, int n_in,
                              void* d_out, int out_size, void* d_ws, size_t ws_size,
                              hipStream_t stream) {
  const float* x    = (const float*)d_in[0];
  const float* w    = (const float*)d_in[1];
  const float* bias = (const float*)d_in[2];

  const int E    = in_sizes[2];          // 64
  const int Hdim = in_sizes[1] / E;      // 4096
  const int T    = in_sizes[0] / Hdim;   // 16384

  unsigned char* ws = (unsigned char*)d_ws;
  unsigned char* w3 = ws;                      // 1.5 MB
  float* pp = (float*)(ws + HI_OFF);           // NPART*T*64 f32 = 32 MB

  const size_t need = (size_t)HI_OFF + (size_t)NPART * T * E_DIM * sizeof(float);
  const int nparts = (ws_size >= need) ? NPART : 1;

  const int nElemGroups = E * Hdim / 16;
  split_w<<<(nElemGroups + 255) / 256, 256, 0, stream>>>(w, w3, Hdim);

  float* outw = (float*)d_out;
  float* outi = outw + (size_t)T * 8;

  dim3 gridG(T / 64, nparts);
  router_mfma<<<gridG, 256, 0, stream>>>(x, w3, bias, outw, outi, pp, T, Hdim);

  if (nparts != 1) {
    router_topk<<<(T + 3) / 4, 256, 0, stream>>>(pp, bias, outw, outi, T);
  }
}

// Round 11
// 133.342 us; speedup vs baseline: 1.0416x; 1.0416x over previous
//
#include <hip/hip_runtime.h>
#include <cmath>

// MoE router via 3-way bf16-split MFMA emulation of fp32 GEMM, compensated
// (TwoSum) accumulation. R11: 20 waves/CU with a LEGAL register budget.
//  - Wave = 16 tokens x 32 experts (2 n-tiles): acc/sum/comp 48->24 VGPR,
//    true live set ~85-90 -> fits the (256,5) 102-VGPR cap WITHOUT spill
//    (R10 regression = spill: needed ~108 under a 102 cap).
//  - Block = 4 waves = 32 tokens x 64 experts (2 tok-groups x 2 exp-groups);
//    expert-split waves write disjoint e-columns -> no extra combine.
//  - grid (T/32) x NPART=4 = 2048 blocks, LDS dbuf 24 KB -> 5 blocks/CU.
//  - Partials: single f32 (err ~3e-8/part; 4-part TwoSum combine exact).
//  - Queue invariant per iter (verified R9/R10): entry [X(c+1)];
//    CONVERT(Xc); STAGE(c+1); LOADX(c+2); MFMA; vmcnt(2) retires
//    X(c+1)+S(c+1); barrier. X(c+2) stays in flight across the barrier.
//
// logits[T,64] = x[T,4096] @ w[64,4096]^T, sigmoid, top-8 on prob+bias,
// weights = p/sum*2.5. Outputs: weights[T,8] f32, then indices[T,8] as f32.

typedef float f32x4 __attribute__((ext_vector_type(4)));
typedef short s16x8 __attribute__((ext_vector_type(8)));
typedef unsigned int u32;
typedef u32 u32x4 __attribute__((ext_vector_type(4)));

#define E_DIM 64
#define KC 32
#define CH_BYTES 12288   // 3 splits * 4 ntiles * 64 lanes * 16B
#define NPART 4
#define HI_OFF (2u << 20)   // partials start at 2 MB (w3 is 1.5 MB)

union V16 { u32x4 u; s16x8 s; };

__device__ __forceinline__ unsigned short f2bf(float f) {
  unsigned u = __float_as_uint(f);
  u += 0x7fffu + ((u >> 16) & 1u);   // round-to-nearest-even
  return (unsigned short)(u >> 16);
}
__device__ __forceinline__ float bf2f(unsigned short s) {
  return __uint_as_float(((unsigned)s) << 16);
}

// ---- kernel W: split w into 3 bf16 planes, in per-lane B-fragment layout ----
// w3[c][s][n][lane]*16B ; lane holds expert e=n*16+(lane&15),
// k = c*32 + (lane>>4)*8 + j  (j=0..7 within the 16B slot).
__global__ __launch_bounds__(256) void split_w(
    const float* __restrict__ w, unsigned char* __restrict__ w3, int Hdim)
{
  const int kpr = Hdim >> 4;                      // 16-elem k-groups per row
  const int g = blockIdx.x * 256 + threadIdx.x;
  const int e = g / kpr;
  const int k0 = (g - e * kpr) * 16;
  if (e >= E_DIM) return;

  const float* src = w + (size_t)e * Hdim + k0;
  float f[16];
#pragma unroll
  for (int i = 0; i < 4; ++i) {
    float4 v = *(const float4*)(src + i * 4);
    f[i*4+0] = v.x; f[i*4+1] = v.y; f[i*4+2] = v.z; f[i*4+3] = v.w;
  }
  unsigned short hs[16], ms[16], ls[16];
#pragma unroll
  for (int i = 0; i < 16; ++i) {
    unsigned short h = f2bf(f[i]);
    float r1 = f[i] - bf2f(h);
    unsigned short m = f2bf(r1);
    float r2 = r1 - bf2f(m);
    hs[i] = h; ms[i] = m; ls[i] = f2bf(r2);
  }
  const int c  = k0 >> 5;                          // chunk of 32 k
  const int n  = e >> 4;                           // n-tile
  const int la = (e & 15) + (((k0 & 31) >> 3) << 4);  // lane of first 8 elems
  unsigned char* base = w3 + (size_t)c * CH_BYTES + n * 1024;

#define STORE_SPLIT(arr, s)                                              \
  do {                                                                   \
    s16x8 pa, pb;                                                        \
    _Pragma("unroll")                                                    \
    for (int j = 0; j < 8; ++j) { pa[j] = (short)arr[j]; pb[j] = (short)arr[8+j]; } \
    *(s16x8*)(base + (s)*4096 + la * 16)        = pa;                    \
    *(s16x8*)(base + (s)*4096 + (la + 16) * 16) = pb;                    \
  } while (0)

  STORE_SPLIT(hs, 0);
  STORE_SPLIT(ms, 1);
  STORE_SPLIT(ls, 2);
#undef STORE_SPLIT
}

// ---- kernel G: 16tok x 32exp waves, dbuf LDS, counted-vmcnt, 20 waves/CU ----
__global__ __launch_bounds__(256, 5) void router_mfma(
    const float* __restrict__ x, const unsigned char* __restrict__ w3,
    float* __restrict__ pp, int T, int Hdim)
{
  __shared__ __align__(16) unsigned char lds[2][CH_BYTES];  // 24 KB

  const int tid  = threadIdx.x;
  const int wid  = tid >> 6;
  const int lane = tid & 63;
  const int lc   = lane & 15;   // token row / expert col / D col
  const int lq   = lane >> 4;   // k-slot group / D row group
  const int tw   = wid >> 1;    // token group (0,1)
  const int eg   = wid & 1;     // expert group (0,1): experts eg*32..eg*32+31
  const int by   = blockIdx.y;
  const int nch  = Hdim / KC / gridDim.y;   // 32 (128 in fallback)
  const int t0   = blockIdx.x * 32;

  const float* xp = x + (size_t)(t0 + tw * 16 + lc) * Hdim
                      + (size_t)by * nch * KC + lq * 8;
  const unsigned char* w3p = w3 + (size_t)by * nch * CH_BYTES;

  f32x4 acc[2], sum_[2], comp[2];
#pragma unroll
  for (int n = 0; n < 2; ++n) {
    acc[n] = (f32x4){0,0,0,0};
    sum_[n] = (f32x4){0,0,0,0};
    comp[n] = (f32x4){0,0,0,0};
  }

#define SB()     __builtin_amdgcn_sched_barrier(0)
#define WAITV2() asm volatile("s_waitcnt vmcnt(2)" ::: "memory")
#define WAITV0() asm volatile("s_waitcnt vmcnt(0)" ::: "memory")
#define BAR()    __builtin_amdgcn_s_barrier()

  // stage chunk c into lds[b]: 3 x 16B per thread, linear (gload_lds-safe)
#define STAGE(c, b)                                                          \
  do {                                                                       \
    const unsigned char* gs = w3p + (size_t)(c) * CH_BYTES + tid * 16;       \
    unsigned char* ld_ = &lds[b][0] + tid * 16;                              \
    _Pragma("unroll")                                                        \
    for (int i = 0; i < 3; ++i)                                              \
      __builtin_amdgcn_global_load_lds(                                      \
          (const __attribute__((address_space(1))) unsigned int*)(gs + i*4096), \
          (__attribute__((address_space(3))) unsigned int*)(ld_ + i*4096),   \
          16, 0, 0);                                                         \
  } while (0)

#define LOADX(c, X)                                                          \
  do {                                                                       \
    X[0] = *(const float4*)(xp + (size_t)(c) * KC);                          \
    X[1] = *(const float4*)(xp + (size_t)(c) * KC + 4);                      \
  } while (0)

  // round-half-up bf16 split + v_perm pack: f = h + m + l, err ~2^-24|f|.
#define SPLIT_PAIR(f0, f1, i, AHU, AMU, ALU)                                 \
  do {                                                                       \
    u32 u0_ = __float_as_uint(f0), u1_ = __float_as_uint(f1);                \
    u32 v0_ = u0_ + 0x8000u, v1_ = u1_ + 0x8000u;                            \
    AHU[i] = __builtin_amdgcn_perm(v1_, v0_, 0x07060302u);                   \
    float r0_ = (f0) - __uint_as_float(v0_ & 0xffff0000u);                   \
    float r1_ = (f1) - __uint_as_float(v1_ & 0xffff0000u);                   \
    u32 w0_ = __float_as_uint(r0_) + 0x8000u;                                \
    u32 w1_ = __float_as_uint(r1_) + 0x8000u;                                \
    AMU[i] = __builtin_amdgcn_perm(w1_, w0_, 0x07060302u);                   \
    float s0_ = r0_ - __uint_as_float(w0_ & 0xffff0000u);                    \
    float s1_ = r1_ - __uint_as_float(w1_ & 0xffff0000u);                    \
    u32 y0_ = __float_as_uint(s0_) + 0x8000u;                                \
    u32 y1_ = __float_as_uint(s1_) + 0x8000u;                                \
    ALU[i] = __builtin_amdgcn_perm(y1_, y0_, 0x07060302u);                   \
  } while (0)

#define CONVERT(X)                                                           \
  do {                                                                       \
    V16 ah_, am_, al_;                                                       \
    SPLIT_PAIR(X[0].x, X[0].y, 0, ah_.u, am_.u, al_.u);                      \
    SPLIT_PAIR(X[0].z, X[0].w, 1, ah_.u, am_.u, al_.u);                      \
    SPLIT_PAIR(X[1].x, X[1].y, 2, ah_.u, am_.u, al_.u);                      \
    SPLIT_PAIR(X[1].z, X[1].w, 3, ah_.u, am_.u, al_.u);                      \
    Aah = ah_.s; Aam = am_.s; Aal = al_.s;                                   \
  } while (0)

  // 12 MFMAs over this wave's 2 n-tiles (expert group eg).
#define MFMA_ALL(b)                                                          \
  do {                                                                       \
    const unsigned char* B_ = &lds[b][0] + eg * 2048 + lane * 16;            \
    __builtin_amdgcn_s_setprio(1);                                           \
    _Pragma("unroll")                                                        \
    for (int n = 0; n < 2; ++n) {                                            \
      s16x8 bh = *(const s16x8*)(B_ + 0*4096 + n*1024);                      \
      s16x8 bm = *(const s16x8*)(B_ + 1*4096 + n*1024);                      \
      s16x8 bl = *(const s16x8*)(B_ + 2*4096 + n*1024);                      \
      acc[n] = __builtin_amdgcn_mfma_f32_16x16x32_bf16(Aah, bh, acc[n], 0,0,0); \
      acc[n] = __builtin_amdgcn_mfma_f32_16x16x32_bf16(Aah, bm, acc[n], 0,0,0); \
      acc[n] = __builtin_amdgcn_mfma_f32_16x16x32_bf16(Aam, bh, acc[n], 0,0,0); \
      acc[n] = __builtin_amdgcn_mfma_f32_16x16x32_bf16(Aah, bl, acc[n], 0,0,0); \
      acc[n] = __builtin_amdgcn_mfma_f32_16x16x32_bf16(Aam, bm, acc[n], 0,0,0); \
      acc[n] = __builtin_amdgcn_mfma_f32_16x16x32_bf16(Aal, bh, acc[n], 0,0,0); \
    }                                                                        \
    __builtin_amdgcn_s_setprio(0);                                           \
  } while (0)

  // TwoSum fold: (sum_,comp) += acc exactly; acc reset. Adds/subs only.
#define FOLD()                                                               \
  do {                                                                       \
    _Pragma("unroll")                                                        \
    for (int n = 0; n < 2; ++n)                                              \
      _Pragma("unroll")                                                      \
      for (int r = 0; r < 4; ++r) {                                          \
        float a_ = acc[n][r];                                                \
        float s_ = sum_[n][r];                                               \
        float t_ = s_ + a_;                                                  \
        float z_ = t_ - s_;                                                  \
        comp[n][r] += (s_ - (t_ - z_)) + (a_ - z_);                          \
        sum_[n][r] = t_;                                                     \
        acc[n][r] = 0.f;                                                     \
      }                                                                      \
  } while (0)

  // Iter c (entry queue [X(c+1)]): consume X(c), stage c+1, reload X(c+2)
  // into the same buffer (WAR). vmcnt(2) retires X(c+1)+S(c+1) exactly,
  // leaves X(c+2) in flight across the barrier.
#define ITER(c, XBUF)                                                        \
  do {                                                                       \
    CONVERT(XBUF);                                                           \
    STAGE((c) + 1, ((c) + 1) & 1);                                           \
    LOADX((c) + 2, XBUF);                                                    \
    SB();                                                                    \
    MFMA_ALL((c) & 1);                                                       \
    WAITV2();                                                                \
    BAR();                                                                   \
    SB();                                                                    \
  } while (0)

  float4 XA[2], XB[2];
  s16x8 Aah, Aam, Aal;

  // prologue: S0, X0, X1; retire S0 for all waves, then barrier.
  STAGE(0, 0);
  LOADX(0, XA);
  LOADX(1, XB);
  asm volatile("s_waitcnt vmcnt(4)" ::: "memory");
  BAR();
  SB();

#pragma unroll 1
  for (int c = 0; c < nch - 4; c += 4) {
    ITER(c + 0, XA);
    ITER(c + 1, XB);
    ITER(c + 2, XA);
    ITER(c + 3, XB);
    FOLD();
  }
  // final 4 chunks: 2 full iters, then 2 compute-only tails
  ITER(nch - 4, XA);
  ITER(nch - 3, XB);
  {  // chunk nch-2 (buf 0): stage last chunk, full drain
    CONVERT(XA);
    STAGE(nch - 1, 1);
    SB();
    MFMA_ALL(0);
    WAITV0();
    BAR();
    SB();
    // chunk nch-1 (buf 1): compute only
    CONVERT(XB);
    SB();
    MFMA_ALL(1);
    FOLD();
  }

  // ---- write partials: single f32 (sum+comp rounded once, err ~3e-8) ----
#pragma unroll
  for (int n = 0; n < 2; ++n)
#pragma unroll
    for (int r = 0; r < 4; ++r) {
      const int tok = t0 + tw * 16 + lq * 4 + r;
      const int e   = eg * 32 + n * 16 + lc;
      const size_t o = ((size_t)tok * NPART + by) * E_DIM + e;
      pp[o] = sum_[n][r] + comp[n][r];
    }
}

// ---- kernel T: TwoSum-combine partials + sigmoid + top-8 ----
__global__ __launch_bounds__(256) void router_topk(
    const float* __restrict__ pp, const float* __restrict__ bias,
    float* __restrict__ outw, float* __restrict__ outi, int T, int nparts)
{
  const int lane = threadIdx.x & 63;
  const int t = blockIdx.x * 4 + (threadIdx.x >> 6);
  if (t >= T) return;

  float s = 0.f, c = 0.f;
  for (int p = 0; p < nparts; ++p) {
    float a = pp[((size_t)t * NPART + p) * E_DIM + lane];
    float tt = s + a;
    float z = tt - s;
    c += (s - (tt - z)) + (a - z);
    s = tt;
  }
  const float logit = s + c;

  const float prob = 1.0f / (1.0f + expf(-logit));
  float v = prob + bias[lane];

  float sum = 0.f, selw = 0.f;
  int seli = 0;
#pragma unroll
  for (int k = 0; k < 8; ++k) {
    float rv = v;
    int   ri = lane;
#pragma unroll
    for (int off = 32; off > 0; off >>= 1) {
      float ov = __shfl_xor(rv, off);
      int   oi = __shfl_xor(ri, off);
      if (ov > rv || (ov == rv && oi < ri)) { rv = ov; ri = oi; }
    }
    float pwin = __shfl(prob, ri);
    sum += pwin;
    if (lane == k)  { selw = pwin; seli = ri; }
    if (lane == ri) v = -INFINITY;
  }

  if (lane < 8) {
    float scale = 2.5f / (sum + 1e-20f);
    outw[(size_t)t * 8 + lane] = selw * scale;
    outi[(size_t)t * 8 + lane] = (float)seli;
  }
}

extern "C" void kernel_launch(void* const* d_in, const int* in_sizes, int n_in,
                              void* d_out, int out_size, void* d_ws, size_t ws_size,
                              hipStream_t stream) {
  const float* x    = (const float*)d_in[0];
  const float* w    = (const float*)d_in[1];
  const float* bias = (const float*)d_in[2];

  const int E    = in_sizes[2];          // 64
  const int Hdim = in_sizes[1] / E;      // 4096
  const int T    = in_sizes[0] / Hdim;   // 16384

  unsigned char* ws = (unsigned char*)d_ws;
  unsigned char* w3 = ws;                      // 1.5 MB
  float* pp = (float*)(ws + HI_OFF);           // NPART*T*64 f32 = 16 MB

  const size_t need = (size_t)HI_OFF + (size_t)NPART * T * E_DIM * sizeof(float);
  const int nparts = (ws_size >= need) ? NPART : 1;

  const int nElemGroups = E * Hdim / 16;
  split_w<<<(nElemGroups + 255) / 256, 256, 0, stream>>>(w, w3, Hdim);

  dim3 gridG(T / 32, nparts);
  router_mfma<<<gridG, 256, 0, stream>>>(x, w3, pp, T, Hdim);

  float* outw = (float*)d_out;
  float* outi = outw + (size_t)T * 8;
  router_topk<<<(T + 3) / 4, 256, 0, stream>>>(pp, bias, outw, outi, T, nparts);
}

// Round 12
// 100.108 us; speedup vs baseline: 1.3874x; 1.3320x over previous
//
#include <hip/hip_runtime.h>
#include <cmath>

// MoE router via 3-way bf16-split MFMA emulation of fp32 GEMM, compensated
// (TwoSum) accumulation. R12 = R9 (measured best, 109.9us) with two safe cuts:
//  - single-f32 partials (sum+comp rounded once, err ~3e-8/part; 4-part
//    TwoSum combine in topk keeps logit err ~25x under the flip point):
//    partial round-trip 32MB -> 16MB.
//  - prologue vmcnt(7)+barrier (R9's first MFMA read other waves' staging
//    without a barrier -- worked by luck).
// Queue invariant per iter (verified): entry [S(c+1)x3, X(c+1)x2];
// issue S(c+2)x3, X(c+2)x2; vmcnt(5) retires exactly S(c+1)+X(c+1);
// barrier. X/S stay >=1.5 iters in flight; nothing young force-drained.
//
// logits[T,64] = x[T,4096] @ w[64,4096]^T, sigmoid, top-8 on prob+bias,
// weights = p/sum*2.5. Outputs: weights[T,8] f32, then indices[T,8] as f32.

typedef float f32x4 __attribute__((ext_vector_type(4)));
typedef short s16x8 __attribute__((ext_vector_type(8)));
typedef unsigned int u32;
typedef u32 u32x4 __attribute__((ext_vector_type(4)));

#define E_DIM 64
#define KC 32
#define CH_BYTES 12288   // 3 splits * 4 ntiles * 64 lanes * 16B
#define NPART 4
#define HI_OFF (2u << 20)   // partials start at 2 MB (w3 is 1.5 MB)

union V16 { u32x4 u; s16x8 s; };

__device__ __forceinline__ unsigned short f2bf(float f) {
  unsigned u = __float_as_uint(f);
  u += 0x7fffu + ((u >> 16) & 1u);   // round-to-nearest-even
  return (unsigned short)(u >> 16);
}
__device__ __forceinline__ float bf2f(unsigned short s) {
  return __uint_as_float(((unsigned)s) << 16);
}

// ---- kernel W: split w into 3 bf16 planes, in per-lane B-fragment layout ----
// w3[c][s][n][lane]*16B ; lane holds expert e=n*16+(lane&15),
// k = c*32 + (lane>>4)*8 + j  (j=0..7 within the 16B slot).
__global__ __launch_bounds__(256) void split_w(
    const float* __restrict__ w, unsigned char* __restrict__ w3, int Hdim)
{
  const int kpr = Hdim >> 4;                      // 16-elem k-groups per row
  const int g = blockIdx.x * 256 + threadIdx.x;
  const int e = g / kpr;
  const int k0 = (g - e * kpr) * 16;
  if (e >= E_DIM) return;

  const float* src = w + (size_t)e * Hdim + k0;
  float f[16];
#pragma unroll
  for (int i = 0; i < 4; ++i) {
    float4 v = *(const float4*)(src + i * 4);
    f[i*4+0] = v.x; f[i*4+1] = v.y; f[i*4+2] = v.z; f[i*4+3] = v.w;
  }
  unsigned short hs[16], ms[16], ls[16];
#pragma unroll
  for (int i = 0; i < 16; ++i) {
    unsigned short h = f2bf(f[i]);
    float r1 = f[i] - bf2f(h);
    unsigned short m = f2bf(r1);
    float r2 = r1 - bf2f(m);
    hs[i] = h; ms[i] = m; ls[i] = f2bf(r2);
  }
  const int c  = k0 >> 5;                          // chunk of 32 k
  const int n  = e >> 4;                           // n-tile
  const int la = (e & 15) + (((k0 & 31) >> 3) << 4);  // lane of first 8 elems
  unsigned char* base = w3 + (size_t)c * CH_BYTES + n * 1024;

#define STORE_SPLIT(arr, s)                                              \
  do {                                                                   \
    s16x8 pa, pb;                                                        \
    _Pragma("unroll")                                                    \
    for (int j = 0; j < 8; ++j) { pa[j] = (short)arr[j]; pb[j] = (short)arr[8+j]; } \
    *(s16x8*)(base + (s)*4096 + la * 16)        = pa;                    \
    *(s16x8*)(base + (s)*4096 + (la + 16) * 16) = pb;                    \
  } while (0)

  STORE_SPLIT(hs, 0);
  STORE_SPLIT(ms, 1);
  STORE_SPLIT(ls, 2);
#undef STORE_SPLIT
}

// ---- kernel G: triple-buffered LDS, stage-2-ahead, counted-vmcnt GEMM ----
__global__ __launch_bounds__(256, 4) void router_mfma(
    const float* __restrict__ x, const unsigned char* __restrict__ w3,
    float* __restrict__ pp, int T, int Hdim)
{
  __shared__ __align__(16) unsigned char lds[3 * CH_BYTES];  // 36 KB

  const int tid  = threadIdx.x;
  const int wid  = tid >> 6;
  const int lane = tid & 63;
  const int lc   = lane & 15;   // token row / expert col / D col
  const int lq   = lane >> 4;   // k-slot group / D row group
  const int by   = blockIdx.y;
  const int npart = gridDim.y;
  const int nch  = Hdim / KC / npart;   // 32 (128 in fallback)
  const int t0   = blockIdx.x * 64;

  const float* xp = x + (size_t)(t0 + wid * 16 + lc) * Hdim
                      + (size_t)by * nch * KC + lq * 8;
  const unsigned char* w3p = w3 + (size_t)by * nch * CH_BYTES;

  f32x4 acc[4], sum_[4], comp[4];
#pragma unroll
  for (int n = 0; n < 4; ++n) {
    acc[n] = (f32x4){0,0,0,0};
    sum_[n] = (f32x4){0,0,0,0};
    comp[n] = (f32x4){0,0,0,0};
  }

#define SB()     __builtin_amdgcn_sched_barrier(0)
#define WAITV5() asm volatile("s_waitcnt vmcnt(5)" ::: "memory")
#define WAITV7() asm volatile("s_waitcnt vmcnt(7)" ::: "memory")
#define WAITV0() asm volatile("s_waitcnt vmcnt(0)" ::: "memory")
#define BAR()    __builtin_amdgcn_s_barrier()

  // stage chunk c into lds+so: 3 x 16B per thread, linear (gload_lds-safe)
#define STAGE(c, so)                                                         \
  do {                                                                       \
    const unsigned char* gs = w3p + (size_t)(c) * CH_BYTES + tid * 16;       \
    unsigned char* ld_ = &lds[0] + (so) + tid * 16;                          \
    _Pragma("unroll")                                                        \
    for (int i = 0; i < 3; ++i)                                              \
      __builtin_amdgcn_global_load_lds(                                      \
          (const __attribute__((address_space(1))) unsigned int*)(gs + i*4096), \
          (__attribute__((address_space(3))) unsigned int*)(ld_ + i*4096),   \
          16, 0, 0);                                                         \
  } while (0)

#define LOADX(c, X)                                                          \
  do {                                                                       \
    X[0] = *(const float4*)(xp + (size_t)(c) * KC);                          \
    X[1] = *(const float4*)(xp + (size_t)(c) * KC + 4);                      \
  } while (0)

  // round-half-up bf16 split + v_perm pack: f = h + m + l, err ~2^-24|f|.
#define SPLIT_PAIR(f0, f1, i, AHU, AMU, ALU)                                 \
  do {                                                                       \
    u32 u0_ = __float_as_uint(f0), u1_ = __float_as_uint(f1);                \
    u32 v0_ = u0_ + 0x8000u, v1_ = u1_ + 0x8000u;                            \
    AHU[i] = __builtin_amdgcn_perm(v1_, v0_, 0x07060302u);                   \
    float r0_ = (f0) - __uint_as_float(v0_ & 0xffff0000u);                   \
    float r1_ = (f1) - __uint_as_float(v1_ & 0xffff0000u);                   \
    u32 w0_ = __float_as_uint(r0_) + 0x8000u;                                \
    u32 w1_ = __float_as_uint(r1_) + 0x8000u;                                \
    AMU[i] = __builtin_amdgcn_perm(w1_, w0_, 0x07060302u);                   \
    float s0_ = r0_ - __uint_as_float(w0_ & 0xffff0000u);                    \
    float s1_ = r1_ - __uint_as_float(w1_ & 0xffff0000u);                    \
    u32 y0_ = __float_as_uint(s0_) + 0x8000u;                                \
    u32 y1_ = __float_as_uint(s1_) + 0x8000u;                                \
    ALU[i] = __builtin_amdgcn_perm(y1_, y0_, 0x07060302u);                   \
  } while (0)

#define CONVERT(X)                                                           \
  do {                                                                       \
    V16 ah_, am_, al_;                                                       \
    SPLIT_PAIR(X[0].x, X[0].y, 0, ah_.u, am_.u, al_.u);                      \
    SPLIT_PAIR(X[0].z, X[0].w, 1, ah_.u, am_.u, al_.u);                      \
    SPLIT_PAIR(X[1].x, X[1].y, 2, ah_.u, am_.u, al_.u);                      \
    SPLIT_PAIR(X[1].z, X[1].w, 3, ah_.u, am_.u, al_.u);                      \
    Aah = ah_.s; Aam = am_.s; Aal = al_.s;                                   \
  } while (0)

  // 24 MFMAs; B loaded per n-pair (6 live transients) to cap VGPR.
#define MFMA_ALL(ro)                                                         \
  do {                                                                       \
    const unsigned char* B_ = &lds[0] + (ro) + lane * 16;                    \
    __builtin_amdgcn_s_setprio(1);                                           \
    _Pragma("unroll")                                                        \
    for (int g = 0; g < 2; ++g) {                                            \
      s16x8 bh0 = *(const s16x8*)(B_ + 0*4096 + (2*g)*1024);                 \
      s16x8 bh1 = *(const s16x8*)(B_ + 0*4096 + (2*g+1)*1024);               \
      s16x8 bm0 = *(const s16x8*)(B_ + 1*4096 + (2*g)*1024);                 \
      s16x8 bm1 = *(const s16x8*)(B_ + 1*4096 + (2*g+1)*1024);               \
      s16x8 bl0 = *(const s16x8*)(B_ + 2*4096 + (2*g)*1024);                 \
      s16x8 bl1 = *(const s16x8*)(B_ + 2*4096 + (2*g+1)*1024);               \
      acc[2*g]   = __builtin_amdgcn_mfma_f32_16x16x32_bf16(Aah, bh0, acc[2*g],   0,0,0); \
      acc[2*g+1] = __builtin_amdgcn_mfma_f32_16x16x32_bf16(Aah, bh1, acc[2*g+1], 0,0,0); \
      acc[2*g]   = __builtin_amdgcn_mfma_f32_16x16x32_bf16(Aah, bm0, acc[2*g],   0,0,0); \
      acc[2*g+1] = __builtin_amdgcn_mfma_f32_16x16x32_bf16(Aah, bm1, acc[2*g+1], 0,0,0); \
      acc[2*g]   = __builtin_amdgcn_mfma_f32_16x16x32_bf16(Aam, bh0, acc[2*g],   0,0,0); \
      acc[2*g+1] = __builtin_amdgcn_mfma_f32_16x16x32_bf16(Aam, bh1, acc[2*g+1], 0,0,0); \
      acc[2*g]   = __builtin_amdgcn_mfma_f32_16x16x32_bf16(Aah, bl0, acc[2*g],   0,0,0); \
      acc[2*g+1] = __builtin_amdgcn_mfma_f32_16x16x32_bf16(Aah, bl1, acc[2*g+1], 0,0,0); \
      acc[2*g]   = __builtin_amdgcn_mfma_f32_16x16x32_bf16(Aam, bm0, acc[2*g],   0,0,0); \
      acc[2*g+1] = __builtin_amdgcn_mfma_f32_16x16x32_bf16(Aam, bm1, acc[2*g+1], 0,0,0); \
      acc[2*g]   = __builtin_amdgcn_mfma_f32_16x16x32_bf16(Aal, bh0, acc[2*g],   0,0,0); \
      acc[2*g+1] = __builtin_amdgcn_mfma_f32_16x16x32_bf16(Aal, bh1, acc[2*g+1], 0,0,0); \
    }                                                                        \
    __builtin_amdgcn_s_setprio(0);                                           \
  } while (0)

  // TwoSum fold: (sum_,comp) += acc exactly; acc reset. Adds/subs only.
#define FOLD()                                                               \
  do {                                                                       \
    _Pragma("unroll")                                                        \
    for (int n = 0; n < 4; ++n)                                              \
      _Pragma("unroll")                                                      \
      for (int r = 0; r < 4; ++r) {                                          \
        float a_ = acc[n][r];                                                \
        float s_ = sum_[n][r];                                               \
        float t_ = s_ + a_;                                                  \
        float z_ = t_ - s_;                                                  \
        comp[n][r] += (s_ - (t_ - z_)) + (a_ - z_);                          \
        sum_[n][r] = t_;                                                     \
        acc[n][r] = 0.f;                                                     \
      }                                                                      \
  } while (0)

  // Steady-state: entering iter c, queue = [S(c+1)x3, X(c+1)x2].
  // Issue S(c+2); consume X(c); re-issue X(c+2) into freed regs; MFMA;
  // vmcnt(5) retires exactly S(c+1)+X(c+1), leaves [S(c+2), X(c+2)].
#define ITER(c, ro, so, XBUF)                                                \
  do {                                                                       \
    STAGE((c) + 2, so);                                                      \
    CONVERT(XBUF);                                                           \
    LOADX((c) + 2, XBUF);                                                    \
    SB();                                                                    \
    MFMA_ALL(ro);                                                            \
    WAITV5();                                                                \
    BAR();                                                                   \
  } while (0)

  float4 XA[2], XB[2];
  s16x8 Aah, Aam, Aal;

  int ro0 = 0, ro1 = CH_BYTES, ro2 = 2 * CH_BYTES;

  // prologue: S0, S1, X0, X1; retire S0 for ALL waves, then barrier
  // (first MFMA reads bytes staged by other waves -- needs the barrier).
  STAGE(0, ro0);
  STAGE(1, ro1);
  LOADX(0, XA);
  LOADX(1, XB);
  WAITV7();
  BAR();

#pragma unroll 1
  for (int c = 0; c < nch - 4; c += 4) {
    ITER(c + 0, ro0, ro2, XA);
    ITER(c + 1, ro1, ro0, XB);
    ITER(c + 2, ro2, ro1, XA);
    ITER(c + 3, ro0, ro2, XB);
    FOLD();
    int t_ = ro0; ro0 = ro1; ro1 = ro2; ro2 = t_;
  }
  // last 4 chunks: 2 full iters (stage nch-2, nch-1), then 2 compute-only
  ITER(nch - 4, ro0, ro2, XA);
  ITER(nch - 3, ro1, ro0, XB);
  {  // chunk nch-2: queue entering = [S(nch-1), X(nch-1)]
    CONVERT(XA);
    SB();
    MFMA_ALL(ro2);
    WAITV0();
    BAR();
    // chunk nch-1: everything drained
    CONVERT(XB);
    SB();
    MFMA_ALL(ro0);
    FOLD();
  }

  // ---- write partials: single f32 (sum+comp rounded once, err ~3e-8) ----
#pragma unroll
  for (int n = 0; n < 4; ++n)
#pragma unroll
    for (int r = 0; r < 4; ++r) {
      const int tok = t0 + wid * 16 + lq * 4 + r;
      const size_t o = ((size_t)tok * npart + by) * E_DIM + n * 16 + lc;
      pp[o] = sum_[n][r] + comp[n][r];
    }
}

// ---- kernel T: TwoSum-combine partials + sigmoid + top-8 ----
__global__ __launch_bounds__(256) void router_topk(
    const float* __restrict__ pp, const float* __restrict__ bias,
    float* __restrict__ outw, float* __restrict__ outi, int T, int nparts)
{
  const int lane = threadIdx.x & 63;
  const int t = blockIdx.x * 4 + (threadIdx.x >> 6);
  if (t >= T) return;

  float s = 0.f, c = 0.f;
  for (int p = 0; p < nparts; ++p) {
    float a = pp[((size_t)t * nparts + p) * E_DIM + lane];
    float tt = s + a;
    float z = tt - s;
    c += (s - (tt - z)) + (a - z);
    s = tt;
  }
  const float logit = s + c;

  const float prob = 1.0f / (1.0f + expf(-logit));
  float v = prob + bias[lane];

  float sum = 0.f, selw = 0.f;
  int seli = 0;
#pragma unroll
  for (int k = 0; k < 8; ++k) {
    float rv = v;
    int   ri = lane;
#pragma unroll
    for (int off = 32; off > 0; off >>= 1) {
      float ov = __shfl_xor(rv, off);
      int   oi = __shfl_xor(ri, off);
      if (ov > rv || (ov == rv && oi < ri)) { rv = ov; ri = oi; }
    }
    float pwin = __shfl(prob, ri);
    sum += pwin;
    if (lane == k)  { selw = pwin; seli = ri; }
    if (lane == ri) v = -INFINITY;
  }

  if (lane < 8) {
    float scale = 2.5f / (sum + 1e-20f);
    outw[(size_t)t * 8 + lane] = selw * scale;
    outi[(size_t)t * 8 + lane] = (float)seli;
  }
}

extern "C" void kernel_launch(void* const* d_in, const int* in_sizes, int n_in,
                              void* d_out, int out_size, void* d_ws, size_t ws_size,
                              hipStream_t stream) {
  const float* x    = (const float*)d_in[0];
  const float* w    = (const float*)d_in[1];
  const float* bias = (const float*)d_in[2];

  const int E    = in_sizes[2];          // 64
  const int Hdim = in_sizes[1] / E;      // 4096
  const int T    = in_sizes[0] / Hdim;   // 16384

  unsigned char* ws = (unsigned char*)d_ws;
  unsigned char* w3 = ws;                      // 1.5 MB
  float* pp = (float*)(ws + HI_OFF);           // NPART*T*64 f32 = 16 MB

  const size_t need = (size_t)HI_OFF + (size_t)NPART * T * E_DIM * sizeof(float);
  const int nparts = (ws_size >= need) ? NPART : 1;

  const int nElemGroups = E * Hdim / 16;
  split_w<<<(nElemGroups + 255) / 256, 256, 0, stream>>>(w, w3, Hdim);

  dim3 gridG(T / 64, nparts);
  router_mfma<<<gridG, 256, 0, stream>>>(x, w3, pp, T, Hdim);

  float* outw = (float*)d_out;
  float* outi = outw + (size_t)T * 8;
  router_topk<<<(T + 3) / 4, 256, 0, stream>>>(pp, bias, outw, outi, T, nparts);
}